// Round 1
// baseline (19023.779 us; speedup 1.0000x reference)
//
#include <hip/hip_runtime.h>

#define TT 1024
#define BB 256
#define CC 41

__device__ __forceinline__ float sigf(float x) {
    // 1/(1+2^(-x*log2e)) ; safe at both extremes
    float t = __builtin_amdgcn_exp2f(-1.4426950408889634f * x);
    return __builtin_amdgcn_rcpf(1.0f + t);
}
__device__ __forceinline__ float tanhf_fast(float x) {
    // 1 - 2/(2^(2x*log2e)+1) ; safe at both extremes
    float t = __builtin_amdgcn_exp2f(2.8853900817779268f * x);
    return fmaf(-2.0f, __builtin_amdgcn_rcpf(t + 1.0f), 1.0f);
}
__device__ __forceinline__ float lane_bcast(float v, int k) {
    return __uint_as_float(__builtin_amdgcn_readlane(__float_as_uint(v), k));
}

// One (batch row, direction) sequence per block. 256 threads = 256 gates,
// 1 gate/thread; per-thread weight rows live in VGPRs for the whole T loop.
//
// Restructured vs previous version (which was ~75% stall, VALUBusy 31%):
//  - ONE __syncthreads per step (was 2): act[] double-buffered; the c/h
//    update is replicated across all 4 waves, h lives in lane-registers
//    (lane u of every wave holds h_u), so no hcur LDS round-trip and no
//    wave0-only serial tail.
//  - x_t staged through a 3-deep rotating LDS buffer, prefetched 2 steps
//    ahead with issue-early/write-late split: the global load for x_{s+2}
//    issues at the top of step s, ds_write lands just before the barrier.
//    Takes the ~500-900cy L3/HBM latency off the per-step critical path.
//  - act ds_reads issue first; the independent x-FMA block hides their
//    LDS latency before the c/h update consumes them.
template <int K>
__global__ __launch_bounds__(256, 2) void lstm_kernel(
    const float* __restrict__ xin,   // [B,T,K]
    const float* __restrict__ w_ih,  // [2,256,K]
    const float* __restrict__ w_hh,  // [2,256,64]
    const float* __restrict__ bias,  // [2,256]
    float* __restrict__ hout)        // [B,T,128], dir writes its 64-half
{
    constexpr int KP = (K + 3) & ~3;   // padded row stride, 16B aligned
    const int b = blockIdx.x;
    const int dir = blockIdx.y;
    const int tid = threadIdx.x;
    const int u = tid & 63;

    float wx[K];
    float wh[64];
    {
        const float* wr = w_ih + ((size_t)dir * 256 + tid) * K;
#pragma unroll
        for (int k = 0; k < K; ++k) wx[k] = wr[k];
        const float* hr = w_hh + ((size_t)dir * 256 + tid) * 64;
#pragma unroll
        for (int k = 0; k < 64; ++k) wh[k] = hr[k];
    }
    const float bg = bias[dir * 256 + tid];

    __shared__ __align__(16) float xs[3][KP];   // rotating x_t staging
    __shared__ float act[2][256];               // double-buffered gate acts

    const float* xb = xin + (size_t)b * TT * K;
    float* hob = hout + (size_t)b * TT * 128 + dir * 64;

    // prologue: stage x for s=0,1; zero pad lanes; zero act[1] so the
    // unconditional step-0 "previous update" is a no-op (c,h stay 0).
    if (tid < K) {
        const int t0 = dir ? (TT - 1) : 0;
        const int t1 = dir ? (TT - 2) : 1;
        xs[0][tid] = xb[(size_t)t0 * K + tid];
        xs[1][tid] = xb[(size_t)t1 * K + tid];
    }
    if (KP > K && tid >= K && tid < KP) {
        xs[0][tid] = 0.f; xs[1][tid] = 0.f; xs[2][tid] = 0.f;
    }
    act[1][tid] = 0.f;

    float hv = 0.f, c = 0.f;
    int rc = 0, rw = 2;   // xs read index (s%3) and write index ((s+2)%3)
    __syncthreads();

    for (int s = 0; s < TT; ++s) {
        // ---- issue prefetch of x_{s+2} (ds_write at loop bottom) ----
        const bool pf = (s + 2 < TT) && (tid < K);
        float xf = 0.f;
        if (pf) {
            const int tp = dir ? (TT - 3 - s) : (s + 2);
            xf = xb[(size_t)tp * K + tid];
        }

        // ---- previous step's activations: issue LDS reads first ----
        const float* ab = act[(s + 1) & 1];
        const float iv = ab[u];
        const float fv = ab[64 + u];
        const float gv = ab[128 + u];
        const float ov = ab[192 + u];

        // ---- x part: broadcast float4 reads from staged LDS row ----
        float ap0 = bg, ap1 = 0.f, ap2 = 0.f, ap3 = 0.f;
        const float4* xv4 = (const float4*)xs[rc];
#pragma unroll
        for (int q = 0; q < KP / 4; ++q) {
            const float4 xv = xv4[q];
            ap0 = fmaf(xv.x, wx[4 * q + 0], ap0);
            if (4 * q + 1 < K) ap1 = fmaf(xv.y, wx[4 * q + 1], ap1);
            if (4 * q + 2 < K) ap2 = fmaf(xv.z, wx[4 * q + 2], ap2);
            if (4 * q + 3 < K) ap3 = fmaf(xv.w, wx[4 * q + 3], ap3);
        }

        // ---- c/h update (replicated across waves; lane u holds unit u) ----
        c = fmaf(fv, c, iv * gv);
        hv = ov * tanhf_fast(c);
        if (s && tid < 64) {
            const int tprev = dir ? (TT - s) : (s - 1);
            hob[(size_t)tprev * 128 + u] = hv;   // fire-and-forget
        }

        // ---- h part: readlane broadcast from register-resident h ----
#pragma unroll
        for (int k = 0; k < 64; ++k) {
            const float hk = lane_bcast(hv, k);
            if ((k & 3) == 0)      ap0 = fmaf(hk, wh[k], ap0);
            else if ((k & 3) == 1) ap1 = fmaf(hk, wh[k], ap1);
            else if ((k & 3) == 2) ap2 = fmaf(hk, wh[k], ap2);
            else                   ap3 = fmaf(hk, wh[k], ap3);
        }

        // ---- activation (gate order i,f,g,o in 64-blocks; wave-uniform) ----
        const float a = (ap0 + ap1) + (ap2 + ap3);
        act[s & 1][tid] = ((tid >> 6) == 2) ? tanhf_fast(a) : sigf(a);

        // ---- land the prefetched x (vmcnt waited here, not at use) ----
        if (pf) xs[rw][tid] = xf;
        __syncthreads();

        rc = (rc == 2) ? 0 : rc + 1;
        rw = (rw == 2) ? 0 : rw + 1;
    }

    // epilogue: final c/h update + store of h_{t(TT-1)}
    {
        const float* ab = act[(TT - 1) & 1];
        c = fmaf(ab[64 + u], c, ab[u] * ab[128 + u]);
        hv = ab[192 + u] * tanhf_fast(c);
        if (tid < 64) {
            const int tlast = dir ? 0 : (TT - 1);
            hob[(size_t)tlast * 128 + u] = hv;
        }
    }
}

// emissions = feats @ lin_w^T + lin_b ; block tile = 64 (b,t) rows x 41 classes
__global__ __launch_bounds__(256, 2) void emis_kernel(
    const float* __restrict__ feats,  // [B*T,128]
    const float* __restrict__ lw,     // [41,128]
    const float* __restrict__ lb,     // [41]
    float* __restrict__ e)            // [B*T,41]
{
    __shared__ float sf[64 * 132];  // padded rows (bank spread)
    __shared__ float swt[41 * 132];
    const int tid = threadIdx.x;
    const size_t bt0 = (size_t)blockIdx.x * 64;

    const float4* fs = (const float4*)(feats + bt0 * 128);
#pragma unroll
    for (int q = 0; q < 8; ++q) {
        const int idx = tid + q * 256;          // 2048 float4s
        const int row = idx >> 5, col = idx & 31;
        *(float4*)&sf[row * 132 + col * 4] = fs[idx];
    }
    for (int idx = tid; idx < 41 * 32; idx += 256) {
        const int row = idx >> 5, col = idx & 31;
        *(float4*)&swt[row * 132 + col * 4] = ((const float4*)lw)[idx];
    }
    __syncthreads();

    const int btg = tid >> 4;          // 16 groups of 4 rows
    const int cg = tid & 15;           // 16 groups of 3 classes
    const int c0 = cg * 3;
    float acc[4][3];
#pragma unroll
    for (int i = 0; i < 4; ++i)
#pragma unroll
        for (int j = 0; j < 3; ++j) acc[i][j] = 0.f;

    for (int k = 0; k < 128; k += 4) {
        float4 fv[4], wv[3];
#pragma unroll
        for (int i = 0; i < 4; ++i) fv[i] = *(const float4*)&sf[(btg * 4 + i) * 132 + k];
#pragma unroll
        for (int j = 0; j < 3; ++j) {
            const int c = (c0 + j < CC) ? (c0 + j) : (CC - 1);
            wv[j] = *(const float4*)&swt[c * 132 + k];
        }
#pragma unroll
        for (int i = 0; i < 4; ++i)
#pragma unroll
            for (int j = 0; j < 3; ++j) {
                acc[i][j] = fmaf(fv[i].x, wv[j].x, acc[i][j]);
                acc[i][j] = fmaf(fv[i].y, wv[j].y, acc[i][j]);
                acc[i][j] = fmaf(fv[i].z, wv[j].z, acc[i][j]);
                acc[i][j] = fmaf(fv[i].w, wv[j].w, acc[i][j]);
            }
    }
    __syncthreads();
    float* so = sf;  // reuse as [64*41] staging for coalesced store
#pragma unroll
    for (int i = 0; i < 4; ++i)
#pragma unroll
        for (int j = 0; j < 3; ++j) {
            const int c = c0 + j;
            if (c < CC) so[(btg * 4 + i) * CC + c] = acc[i][j] + lb[c];
        }
    __syncthreads();
    float* eo = e + bt0 * CC;
    for (int q = tid; q < 64 * CC; q += 256) eo[q] = so[q];
}

// One wave per batch row; backpointers in LDS; in-kernel backtrace.
__global__ __launch_bounds__(64, 1) void viterbi_kernel(
    const float* __restrict__ e,   // [B,T,41]
    const float* __restrict__ st,  // [41]
    const float* __restrict__ en,  // [41]
    const float* __restrict__ tr,  // [41,41]
    int* __restrict__ out)         // [B,T]
{
    const int b = blockIdx.x;
    const int lane = threadIdx.x;
    __shared__ unsigned char bp[TT][CC];
    __shared__ float sc[2][CC];
    const int c = (lane < CC) ? lane : (CC - 1);
    float trc[CC];
#pragma unroll
    for (int p = 0; p < CC; ++p) trc[p] = tr[p * CC + c];

    const float* eb = e + (size_t)b * TT * CC;
    const float NEG = -3.0e38f;
    if (lane < CC) sc[0][lane] = st[lane] + eb[lane];
    __syncthreads();

    for (int t = 1; t < TT; ++t) {
        const float* scp = sc[(t - 1) & 1];
        float best = NEG;
        int bi = 0;
#pragma unroll
        for (int p = 0; p < CC; ++p) {
            const float v = scp[p] + trc[p];
            if (v > best) { best = v; bi = p; }   // strict > : first-index ties
        }
        if (lane < CC) {
            sc[t & 1][lane] = best + eb[(size_t)t * CC + lane];
            bp[t][lane] = (unsigned char)bi;
        }
        __syncthreads();
    }

    float fin = (lane < CC) ? sc[(TT - 1) & 1][lane] + en[lane] : NEG;
    int idx = lane;
#pragma unroll
    for (int off = 32; off; off >>= 1) {
        const float v2 = __shfl_down(fin, off, 64);
        const int i2 = __shfl_down(idx, off, 64);
        if (v2 > fin || (v2 == fin && i2 < idx)) { fin = v2; idx = i2; }
    }
    int tag = __shfl(idx, 0, 64);
    if (lane == 0) {
        int* ob = out + (size_t)b * TT;
        ob[TT - 1] = tag;
        for (int t = TT - 1; t >= 1; --t) {
            tag = bp[t][tag];
            ob[t - 1] = tag;
        }
    }
}

extern "C" void kernel_launch(void* const* d_in, const int* in_sizes, int n_in,
                              void* d_out, int out_size, void* d_ws, size_t ws_size,
                              hipStream_t stream) {
    const float* x       = (const float*)d_in[0];   // [B,T,39]
    const float* w_ih_l0 = (const float*)d_in[1];   // [2,256,39]
    const float* w_hh_l0 = (const float*)d_in[2];   // [2,256,64]
    const float* b_l0    = (const float*)d_in[3];   // [2,256]
    const float* w_ih_r  = (const float*)d_in[4];   // [2,2,256,128]
    const float* w_hh_r  = (const float*)d_in[5];   // [2,2,256,64]
    const float* b_r     = (const float*)d_in[6];   // [2,2,256]
    const float* lin_w   = (const float*)d_in[7];   // [41,128]
    const float* lin_b   = (const float*)d_in[8];   // [41]
    const float* crf_s   = (const float*)d_in[9];   // [41]
    const float* crf_e   = (const float*)d_in[10];  // [41]
    const float* crf_t   = (const float*)d_in[11];  // [41,41]
    int* out = (int*)d_out;

    float* buf0 = (float*)d_ws;                         // [B,T,128] = 128 MiB
    float* buf1 = buf0 + (size_t)BB * TT * 128;         // [B,T,128] = 128 MiB

    dim3 grid(BB, 2);
    // layer 0 (input dim 39): buf0 <- x
    lstm_kernel<39><<<grid, 256, 0, stream>>>(x, w_ih_l0, w_hh_l0, b_l0, buf0);
    // layer 1: buf1 <- buf0
    lstm_kernel<128><<<grid, 256, 0, stream>>>(buf0, w_ih_r, w_hh_r, b_r, buf1);
    // layer 2: buf0 <- buf1
    lstm_kernel<128><<<grid, 256, 0, stream>>>(
        buf1, w_ih_r + 2 * 256 * 128, w_hh_r + 2 * 256 * 64, b_r + 2 * 256, buf0);
    // emissions: buf1 <- buf0 (L2 output), [B*T,41]
    emis_kernel<<<BB * TT / 64, 256, 0, stream>>>(buf0, lin_w, lin_b, buf1);
    // viterbi + backtrace
    viterbi_kernel<<<BB, 64, 0, stream>>>(buf1, crf_s, crf_e, crf_t, out);
}

// Round 2
// 6122.604 us; speedup vs baseline: 3.1071x; 3.1071x over previous
//
#include <hip/hip_runtime.h>

#define TT 1024
#define BB 256
#define CC 41

__device__ __forceinline__ float sigf(float x) {
    float t = __builtin_amdgcn_exp2f(-1.4426950408889634f * x);
    return __builtin_amdgcn_rcpf(1.0f + t);
}
__device__ __forceinline__ float tanhf_fast(float x) {
    float t = __builtin_amdgcn_exp2f(2.8853900817779268f * x);
    return fmaf(-2.0f, __builtin_amdgcn_rcpf(t + 1.0f), 1.0f);
}
__device__ __forceinline__ float lane_bcast(float v, int k) {
    return __uint_as_float(__builtin_amdgcn_readlane(__float_as_uint(v), k));
}

// ---------------------------------------------------------------------------
// gx GEMM: gout[b][i][g] = sum_k X[b][t0+i][k] * W[dirsel*256+g][k] + bias[g]
// for i in [0,SC), g in [0,256). Tile 64 rows x 64 cols, 256 threads,
// 4x4 acc per thread with 16-strided rows/cols (bank-conflict-free reads:
// per-wave xv = 16 distinct rows broadcast x4, wv = 4 distinct rows bcast x16).
// ---------------------------------------------------------------------------
template <int K>
__global__ __launch_bounds__(256, 2) void gx_gemm(
    const float* __restrict__ X,     // [B,T,K]
    const float* __restrict__ W,     // [2,256,K]
    const float* __restrict__ bias,  // [2,256]
    float* __restrict__ gout,        // [B,SC,256]
    int t0, int dirsel, int SC)
{
    constexpr int KP = (K + 3) & ~3;
    constexpr int ST = KP + 4;       // row stride (floats); ST*4 % 16 == 0
    __shared__ float sx[64 * ST];
    __shared__ float sw[64 * ST];
    const int tid = threadIdx.x;
    const int r0 = blockIdx.x * 64;
    const int cb = blockIdx.y;       // col block: cols cb*64 .. +64
    const int b = r0 / SC;           // SC is a multiple of 64 -> single b per tile
    const int i0 = r0 - b * SC;
    const float* xbase = X + ((size_t)b * TT + t0 + i0) * K;
    const float* wbase = W + ((size_t)dirsel * 256 + cb * 64) * K;

    if constexpr ((K & 3) == 0) {
        constexpr int K4 = K / 4;
        for (int idx = tid; idx < 64 * K4; idx += 256) {
            const int row = idx / K4, c4 = idx % K4;
            *(float4*)&sx[row * ST + c4 * 4] =
                ((const float4*)(xbase + (size_t)row * K))[c4];
        }
        for (int idx = tid; idx < 64 * K4; idx += 256) {
            const int row = idx / K4, c4 = idx % K4;
            *(float4*)&sw[row * ST + c4 * 4] =
                ((const float4*)(wbase + (size_t)row * K))[c4];
        }
    } else {
        for (int idx = tid; idx < 64 * KP; idx += 256) {
            const int row = idx / KP, col = idx % KP;
            sx[row * ST + col] = (col < K) ? xbase[(size_t)row * K + col] : 0.f;
        }
        for (int idx = tid; idx < 64 * KP; idx += 256) {
            const int row = idx / KP, col = idx % KP;
            sw[row * ST + col] = (col < K) ? wbase[(size_t)row * K + col] : 0.f;
        }
    }
    __syncthreads();

    const int rg = tid & 15;   // rows rg + 16*ii
    const int cg = tid >> 4;   // cols cg + 16*jj
    float acc[4][4] = {};
#pragma unroll
    for (int k = 0; k < KP; k += 4) {
        float4 xv[4], wv[4];
#pragma unroll
        for (int ii = 0; ii < 4; ++ii)
            xv[ii] = *(const float4*)&sx[(rg + 16 * ii) * ST + k];
#pragma unroll
        for (int jj = 0; jj < 4; ++jj)
            wv[jj] = *(const float4*)&sw[(cg + 16 * jj) * ST + k];
#pragma unroll
        for (int ii = 0; ii < 4; ++ii)
#pragma unroll
            for (int jj = 0; jj < 4; ++jj) {
                acc[ii][jj] = fmaf(xv[ii].x, wv[jj].x, acc[ii][jj]);
                acc[ii][jj] = fmaf(xv[ii].y, wv[jj].y, acc[ii][jj]);
                acc[ii][jj] = fmaf(xv[ii].z, wv[jj].z, acc[ii][jj]);
                acc[ii][jj] = fmaf(xv[ii].w, wv[jj].w, acc[ii][jj]);
            }
    }
    float bb[4];
#pragma unroll
    for (int jj = 0; jj < 4; ++jj)
        bb[jj] = bias[dirsel * 256 + cb * 64 + cg + 16 * jj];
    float* orow = gout + ((size_t)b * SC + i0) * 256 + cb * 64;
#pragma unroll
    for (int ii = 0; ii < 4; ++ii)
#pragma unroll
        for (int jj = 0; jj < 4; ++jj)
            orow[(size_t)(rg + 16 * ii) * 256 + cg + 16 * jj] = acc[ii][jj] + bb[jj];
}

// ---------------------------------------------------------------------------
// Slim recurrence: gates = gx[t] + h @ w_hh^T. Only wh[64] lives in VGPRs
// (~90 VGPRs total -- the round-0 allocator held this). One barrier/step,
// act double-buffered, c/h replicated across the 4 waves (lane u = unit u),
// gx prefetched 2 steps ahead into registers (coalesced 1KB/step/block).
// Chunked over s in [s0, s0+SC); c + act state carried through `state`.
// ---------------------------------------------------------------------------
__global__ __launch_bounds__(256, 2) void rec_kernel(
    const float* __restrict__ gxA,   // [B,SC,256] dir0 (i = s_local)
    const float* __restrict__ gxB,   // [B,SC,256] dir1 (i = SC-1-s_local)
    const float* __restrict__ w_hh,  // [2,256,64]
    float* __restrict__ hout,        // [B,T,128], dir writes its 64-half
    float* __restrict__ state,       // [B,2,320]: c[64] + act[256]
    int s0, int SC)
{
    const int b = blockIdx.x;
    const int dir = blockIdx.y;
    const int tid = threadIdx.x;
    const int u = tid & 63;

    float wh[64];
    {
        const float* hr = w_hh + ((size_t)dir * 256 + tid) * 64;
#pragma unroll
        for (int k = 0; k < 64; ++k) wh[k] = hr[k];
    }

    __shared__ float act[2][256];
    float* st = state + ((size_t)b * 2 + dir) * 320;

    float c, av;
    if (s0 == 0) { c = 0.f; av = 0.f; }
    else         { c = st[u]; av = st[64 + tid]; }
    act[(s0 + 1) & 1][tid] = av;   // act(s0-1) into buffer (s0-1)&1
    float hv = 0.f;
    __syncthreads();

    const float* gx = dir ? gxB : gxA;
    const size_t gbase = (size_t)b * SC * 256 + tid;
    float gp0, gp1;
    {
        const int i0 = dir ? (SC - 1) : 0;
        const int i1 = dir ? (SC - 2) : 1;
        gp0 = gx[gbase + (size_t)i0 * 256];
        gp1 = gx[gbase + (size_t)i1 * 256];
    }
    float* hob = hout + (size_t)b * TT * 128 + dir * 64;

    for (int sl = 0; sl < SC; ++sl) {
        const int s = s0 + sl;

        // prefetch gx for sl+2 (lands 2 steps later)
        float gp2 = 0.f;
        if (sl + 2 < SC) {
            const int ip = dir ? (SC - 3 - sl) : (sl + 2);
            gp2 = gx[gbase + (size_t)ip * 256];
        }

        // previous step's activations
        const float* ab = act[(s + 1) & 1];
        const float iv = ab[u];
        const float fv = ab[64 + u];
        const float gv = ab[128 + u];
        const float ov = ab[192 + u];

        c = fmaf(fv, c, iv * gv);
        hv = ov * tanhf_fast(c);
        if (s && tid < 64) {
            const int tprev = dir ? (TT - s) : (s - 1);
            hob[(size_t)tprev * 128 + u] = hv;   // fire-and-forget
        }

        // h part: readlane broadcast from register-resident h
        float ap0 = gp0, ap1 = 0.f, ap2 = 0.f, ap3 = 0.f;
#pragma unroll
        for (int k = 0; k < 64; ++k) {
            const float hk = lane_bcast(hv, k);
            if ((k & 3) == 0)      ap0 = fmaf(hk, wh[k], ap0);
            else if ((k & 3) == 1) ap1 = fmaf(hk, wh[k], ap1);
            else if ((k & 3) == 2) ap2 = fmaf(hk, wh[k], ap2);
            else                   ap3 = fmaf(hk, wh[k], ap3);
        }

        const float a = (ap0 + ap1) + (ap2 + ap3);
        act[s & 1][tid] = ((tid >> 6) == 2) ? tanhf_fast(a) : sigf(a);

        gp0 = gp1; gp1 = gp2;
        __syncthreads();
    }

    if (s0 + SC == TT) {
        // final c/h update + last h store
        const float* ab = act[(TT - 1) & 1];
        const float cf = fmaf(ab[64 + u], c, ab[u] * ab[128 + u]);
        const float hf = ab[192 + u] * tanhf_fast(cf);
        if (tid < 64) {
            const int tlast = dir ? 0 : (TT - 1);
            hob[(size_t)tlast * 128 + u] = hf;
        }
    } else {
        if (tid < 64) st[u] = c;                        // replicated -> wave0
        st[64 + tid] = act[(s0 + SC + 1) & 1][tid];     // act(s_end-1)
    }
}

// ---------------------------------------------------------------------------
// Fallback fused LSTM (exact round-0 kernel, known-good at ~2ms/layer),
// used only if ws_size cannot fit the gx chunk buffers.
// ---------------------------------------------------------------------------
template <int K, int NT>
__global__ __launch_bounds__(NT, 2) void lstm_fused(
    const float* __restrict__ xin, const float* __restrict__ w_ih,
    const float* __restrict__ w_hh, const float* __restrict__ bias,
    float* __restrict__ hout)
{
    constexpr int GT = 256 / NT;
    const int b = blockIdx.x;
    const int dir = blockIdx.y;
    const int tid = threadIdx.x;

    float wx[GT][K];
    float wh[GT][64];
    float bg[GT];
#pragma unroll
    for (int j = 0; j < GT; ++j) {
        const int g = tid + j * NT;
        const float* wr = w_ih + ((size_t)dir * 256 + g) * K;
#pragma unroll
        for (int k = 0; k < K; ++k) wx[j][k] = wr[k];
        const float* hr = w_hh + ((size_t)dir * 256 + g) * 64;
#pragma unroll
        for (int k = 0; k < 64; ++k) wh[j][k] = hr[k];
        bg[j] = bias[dir * 256 + g];
    }

    __shared__ float act[256];
    __shared__ float hcur[64];
    float c = 0.0f;
    if (tid < 64) hcur[tid] = 0.0f;
    __syncthreads();

    const float* xb = xin + (size_t)b * TT * K;
    float* hob = hout + (size_t)b * TT * 128 + dir * 64;

    for (int s = 0; s < TT; ++s) {
        const int t = dir ? (TT - 1 - s) : s;
        const float* xt = xb + (size_t)t * K;

        float ap[4][GT];
#pragma unroll
        for (int j = 0; j < GT; ++j) {
            ap[0][j] = bg[j]; ap[1][j] = 0.f; ap[2][j] = 0.f; ap[3][j] = 0.f;
        }

        if constexpr ((K & 3) == 0) {
            const float4* xt4 = (const float4*)xt;
#pragma unroll
            for (int q = 0; q < K / 4; ++q) {
                const float4 xv = xt4[q];
#pragma unroll
                for (int j = 0; j < GT; ++j) {
                    ap[0][j] = fmaf(xv.x, wx[j][4 * q + 0], ap[0][j]);
                    ap[1][j] = fmaf(xv.y, wx[j][4 * q + 1], ap[1][j]);
                    ap[2][j] = fmaf(xv.z, wx[j][4 * q + 2], ap[2][j]);
                    ap[3][j] = fmaf(xv.w, wx[j][4 * q + 3], ap[3][j]);
                }
            }
        } else {
#pragma unroll
            for (int k = 0; k < K; ++k) {
                const float xv = xt[k];
#pragma unroll
                for (int j = 0; j < GT; ++j)
                    ap[k & 3][j] = fmaf(xv, wx[j][k], ap[k & 3][j]);
            }
        }

        const float hvv = hcur[tid & 63];
#pragma unroll
        for (int k = 0; k < 64; ++k) {
            const float hk = lane_bcast(hvv, k);
#pragma unroll
            for (int j = 0; j < GT; ++j)
                ap[k & 3][j] = fmaf(hk, wh[j][k], ap[k & 3][j]);
        }

#pragma unroll
        for (int j = 0; j < GT; ++j) {
            const float a = (ap[0][j] + ap[1][j]) + (ap[2][j] + ap[3][j]);
            const int g = tid + j * NT;
            act[g] = ((g >> 6) == 2) ? tanhf_fast(a) : sigf(a);
        }
        __syncthreads();

        if (tid < 64) {
            const float iv = act[tid], fv = act[64 + tid];
            const float gv = act[128 + tid], ov = act[192 + tid];
            c = fmaf(fv, c, iv * gv);
            const float h = ov * tanhf_fast(c);
            hcur[tid] = h;
            hob[(size_t)t * 128 + tid] = h;
        }
        __syncthreads();
    }
}

// emissions = feats @ lin_w^T + lin_b ; block tile = 64 (b,t) rows x 41 classes
__global__ __launch_bounds__(256, 2) void emis_kernel(
    const float* __restrict__ feats,  // [B*T,128]
    const float* __restrict__ lw,     // [41,128]
    const float* __restrict__ lb,     // [41]
    float* __restrict__ e)            // [B*T,41]
{
    __shared__ float sf[64 * 132];
    __shared__ float swt[41 * 132];
    const int tid = threadIdx.x;
    const size_t bt0 = (size_t)blockIdx.x * 64;

    const float4* fs = (const float4*)(feats + bt0 * 128);
#pragma unroll
    for (int q = 0; q < 8; ++q) {
        const int idx = tid + q * 256;
        const int row = idx >> 5, col = idx & 31;
        *(float4*)&sf[row * 132 + col * 4] = fs[idx];
    }
    for (int idx = tid; idx < 41 * 32; idx += 256) {
        const int row = idx >> 5, col = idx & 31;
        *(float4*)&swt[row * 132 + col * 4] = ((const float4*)lw)[idx];
    }
    __syncthreads();

    const int btg = tid >> 4;
    const int cg = tid & 15;
    const int c0 = cg * 3;
    float acc[4][3];
#pragma unroll
    for (int i = 0; i < 4; ++i)
#pragma unroll
        for (int j = 0; j < 3; ++j) acc[i][j] = 0.f;

    for (int k = 0; k < 128; k += 4) {
        float4 fv[4], wv[3];
#pragma unroll
        for (int i = 0; i < 4; ++i) fv[i] = *(const float4*)&sf[(btg * 4 + i) * 132 + k];
#pragma unroll
        for (int j = 0; j < 3; ++j) {
            const int c = (c0 + j < CC) ? (c0 + j) : (CC - 1);
            wv[j] = *(const float4*)&swt[c * 132 + k];
        }
#pragma unroll
        for (int i = 0; i < 4; ++i)
#pragma unroll
            for (int j = 0; j < 3; ++j) {
                acc[i][j] = fmaf(fv[i].x, wv[j].x, acc[i][j]);
                acc[i][j] = fmaf(fv[i].y, wv[j].y, acc[i][j]);
                acc[i][j] = fmaf(fv[i].z, wv[j].z, acc[i][j]);
                acc[i][j] = fmaf(fv[i].w, wv[j].w, acc[i][j]);
            }
    }
    __syncthreads();
    float* so = sf;
#pragma unroll
    for (int i = 0; i < 4; ++i)
#pragma unroll
        for (int j = 0; j < 3; ++j) {
            const int c = c0 + j;
            if (c < CC) so[(btg * 4 + i) * CC + c] = acc[i][j] + lb[c];
        }
    __syncthreads();
    float* eo = e + bt0 * CC;
    for (int q = tid; q < 64 * CC; q += 256) eo[q] = so[q];
}

// One wave per batch row; backpointers in LDS; in-kernel backtrace.
__global__ __launch_bounds__(64, 1) void viterbi_kernel(
    const float* __restrict__ e, const float* __restrict__ st,
    const float* __restrict__ en, const float* __restrict__ tr,
    int* __restrict__ out)
{
    const int b = blockIdx.x;
    const int lane = threadIdx.x;
    __shared__ unsigned char bp[TT][CC];
    __shared__ float sc[2][CC];
    const int c = (lane < CC) ? lane : (CC - 1);
    float trc[CC];
#pragma unroll
    for (int p = 0; p < CC; ++p) trc[p] = tr[p * CC + c];

    const float* eb = e + (size_t)b * TT * CC;
    const float NEG = -3.0e38f;
    if (lane < CC) sc[0][lane] = st[lane] + eb[lane];
    __syncthreads();

    for (int t = 1; t < TT; ++t) {
        const float* scp = sc[(t - 1) & 1];
        float best = NEG;
        int bi = 0;
#pragma unroll
        for (int p = 0; p < CC; ++p) {
            const float v = scp[p] + trc[p];
            if (v > best) { best = v; bi = p; }
        }
        if (lane < CC) {
            sc[t & 1][lane] = best + eb[(size_t)t * CC + lane];
            bp[t][lane] = (unsigned char)bi;
        }
        __syncthreads();
    }

    float fin = (lane < CC) ? sc[(TT - 1) & 1][lane] + en[lane] : NEG;
    int idx = lane;
#pragma unroll
    for (int off = 32; off; off >>= 1) {
        const float v2 = __shfl_down(fin, off, 64);
        const int i2 = __shfl_down(idx, off, 64);
        if (v2 > fin || (v2 == fin && i2 < idx)) { fin = v2; idx = i2; }
    }
    int tag = __shfl(idx, 0, 64);
    if (lane == 0) {
        int* ob = out + (size_t)b * TT;
        ob[TT - 1] = tag;
        for (int t = TT - 1; t >= 1; --t) {
            tag = bp[t][tag];
            ob[t - 1] = tag;
        }
    }
}

extern "C" void kernel_launch(void* const* d_in, const int* in_sizes, int n_in,
                              void* d_out, int out_size, void* d_ws, size_t ws_size,
                              hipStream_t stream) {
    const float* x       = (const float*)d_in[0];
    const float* w_ih_l0 = (const float*)d_in[1];
    const float* w_hh_l0 = (const float*)d_in[2];
    const float* b_l0    = (const float*)d_in[3];
    const float* w_ih_r  = (const float*)d_in[4];
    const float* w_hh_r  = (const float*)d_in[5];
    const float* b_r     = (const float*)d_in[6];
    const float* lin_w   = (const float*)d_in[7];
    const float* lin_b   = (const float*)d_in[8];
    const float* crf_s   = (const float*)d_in[9];
    const float* crf_e   = (const float*)d_in[10];
    const float* crf_t   = (const float*)d_in[11];
    int* out = (int*)d_out;

    const size_t HB = (size_t)BB * TT * 128 * sizeof(float);   // 134 MiB
    const size_t stateB = (size_t)BB * 2 * 320 * sizeof(float);

    // pick the largest T-chunk whose gx buffers fit the workspace
    int SC = 0;
    for (int cand = 1024; cand >= 128; cand >>= 1) {
        const size_t need = 2 * HB + 2 * (size_t)BB * cand * 256 * sizeof(float) + stateB;
        if (ws_size >= need) { SC = cand; break; }
    }

    float* buf0 = (float*)d_ws;
    float* buf1 = buf0 + (size_t)BB * TT * 128;

    if (SC) {
        float* gxA = buf1 + (size_t)BB * TT * 128;
        float* gxB = gxA + (size_t)BB * SC * 256;
        float* stb = gxB + (size_t)BB * SC * 256;
        const int nch = TT / SC;
        const dim3 gg(BB * SC / 64, 4);
        const dim3 gr(BB, 2);

        // layer 0 (K=39): x -> buf0
        for (int c2 = 0; c2 < nch; ++c2) {
            gx_gemm<39><<<gg, 256, 0, stream>>>(x, w_ih_l0, b_l0, gxA, c2 * SC, 0, SC);
            gx_gemm<39><<<gg, 256, 0, stream>>>(x, w_ih_l0, b_l0, gxB, TT - (c2 + 1) * SC, 1, SC);
            rec_kernel<<<gr, 256, 0, stream>>>(gxA, gxB, w_hh_l0, buf0, stb, c2 * SC, SC);
        }
        // layer 1 (K=128): buf0 -> buf1
        for (int c2 = 0; c2 < nch; ++c2) {
            gx_gemm<128><<<gg, 256, 0, stream>>>(buf0, w_ih_r, b_r, gxA, c2 * SC, 0, SC);
            gx_gemm<128><<<gg, 256, 0, stream>>>(buf0, w_ih_r, b_r, gxB, TT - (c2 + 1) * SC, 1, SC);
            rec_kernel<<<gr, 256, 0, stream>>>(gxA, gxB, w_hh_r, buf1, stb, c2 * SC, SC);
        }
        // layer 2 (K=128): buf1 -> buf0
        const float* wih2 = w_ih_r + 2 * 256 * 128;
        const float* whh2 = w_hh_r + 2 * 256 * 64;
        const float* b2   = b_r + 2 * 256;
        for (int c2 = 0; c2 < nch; ++c2) {
            gx_gemm<128><<<gg, 256, 0, stream>>>(buf1, wih2, b2, gxA, c2 * SC, 0, SC);
            gx_gemm<128><<<gg, 256, 0, stream>>>(buf1, wih2, b2, gxB, TT - (c2 + 1) * SC, 1, SC);
            rec_kernel<<<gr, 256, 0, stream>>>(gxA, gxB, whh2, buf0, stb, c2 * SC, SC);
        }
    } else {
        // fallback: exact round-0 fused path (fits in 256 MiB)
        dim3 grid(BB, 2);
        lstm_fused<39, 128><<<grid, 128, 0, stream>>>(x, w_ih_l0, w_hh_l0, b_l0, buf0);
        lstm_fused<128, 256><<<grid, 256, 0, stream>>>(buf0, w_ih_r, w_hh_r, b_r, buf1);
        lstm_fused<128, 256><<<grid, 256, 0, stream>>>(
            buf1, w_ih_r + 2 * 256 * 128, w_hh_r + 2 * 256 * 64, b_r + 2 * 256, buf0);
    }

    emis_kernel<<<BB * TT / 64, 256, 0, stream>>>(buf0, lin_w, lin_b, buf1);
    viterbi_kernel<<<BB, 64, 0, stream>>>(buf1, crf_s, crf_e, crf_t, out);
}